// Round 3
// baseline (436.500 us; speedup 1.0000x reference)
//
#include <hip/hip_runtime.h>
#include <math.h>

#define NPTS  65536
#define KNN   10
#define PK    25
#define NCOUT 64
#define GRIDB 10          // pooling grid (cell 0.1) — must match reference
#define NSEG  1000
#define GRIDC 20          // kNN search grid (cell 0.05)
#define NCELL (GRIDC*GRIDC*GRIDC)
#define CELLK 0.05f
#define R0SQ  0.002025f   // (0.045)^2 candidate prune radius
#define CAND_CAP 384      // 3^3 neighborhood: mean 221, +6.6 sigma < 384

// ---- workspace layout (bytes) ----
#define OFF_SORTED  0           // float4 sorted[65536]
#define OFF_HIST    1048576     // int hist[8000]
#define OFF_CSTART  1080576     // int cstart[8001]
#define OFF_CURSOR  1112580     // int cursor[8000]
#define OFF_POOL    1144592     // float: counts[1000] | spt[1000*3] | sinf[1000*25]

__device__ __forceinline__ int cell_of(float px, float py, float pz) {
    int gx = min((int)(px * (float)GRIDC), GRIDC - 1);
    int gy = min((int)(py * (float)GRIDC), GRIDC - 1);
    int gz = min((int)(pz * (float)GRIDC), GRIDC - 1);
    return (gx * GRIDC + gy) * GRIDC + gz;
}

__global__ __launch_bounds__(256) void hist_kernel(
    const float* __restrict__ pts, int* __restrict__ hist)
{
    int g = blockIdx.x * 256 + threadIdx.x;
    float px = pts[g*3+0], py = pts[g*3+1], pz = pts[g*3+2];
    atomicAdd(&hist[cell_of(px, py, pz)], 1);
}

__global__ __launch_bounds__(256) void scan_kernel(
    const int* __restrict__ hist, int* __restrict__ cstart, int* __restrict__ cursor)
{
    __shared__ int part[256];
    const int t = threadIdx.x;
    const int base = t * 32;                       // 256*32 = 8192 >= 8000
    int s = 0;
    for (int i = 0; i < 32; ++i) {
        int c = base + i;
        s += (c < NCELL) ? hist[c] : 0;
    }
    part[t] = s;
    __syncthreads();
    for (int off = 1; off < 256; off <<= 1) {      // Hillis-Steele inclusive
        int v = (t >= off) ? part[t - off] : 0;
        __syncthreads();
        part[t] += v;
        __syncthreads();
    }
    int run = (t == 0) ? 0 : part[t - 1];
    for (int i = 0; i < 32; ++i) {
        int c = base + i;
        if (c < NCELL) {
            cstart[c] = run;
            cursor[c] = run;
            run += hist[c];
        }
    }
    if (t == 255) cstart[NCELL] = run;
}

__global__ __launch_bounds__(256) void scatter_kernel(
    const float* __restrict__ pts, int* __restrict__ cursor, float4* __restrict__ sorted)
{
    int g = blockIdx.x * 256 + threadIdx.x;
    float px = pts[g*3+0], py = pts[g*3+1], pz = pts[g*3+2];
    int c = cell_of(px, py, pz);
    int pos = atomicAdd(&cursor[c], 1);
    sorted[pos] = make_float4(px, py, pz, 0.f);
}

// One wave (64 threads) per fine cell. Lane = one query of that cell.
__global__ __launch_bounds__(64) void knn_kpconv_pool(
    const float4* __restrict__ sorted,
    const int*    __restrict__ cstart,
    const float*  __restrict__ kern,
    float*        __restrict__ pool)
{
    __shared__ float4 cand[CAND_CAP];
    __shared__ float4 kpt[PK];

    const int tid = threadIdx.x;
    const int c   = blockIdx.x;
    const int cz  = c % GRIDC;
    const int cy  = (c / GRIDC) % GRIDC;
    const int cx  = c / (GRIDC * GRIDC);

    const int qb = cstart[c], qe = cstart[c + 1];
    const int qn = qe - qb;
    if (qn == 0) return;

    if (tid < PK)
        kpt[tid] = make_float4(kern[tid*3+0], kern[tid*3+1], kern[tid*3+2], 0.f);

    // ---- stage 3^3 neighborhood into LDS as 9 z-columns (center first)
    const int dxo[9] = {0,-1,1, 0,0,-1,-1, 1,1};
    const int dyo[9] = {0, 0,0,-1,1,-1, 1,-1,1};
    const int zlo = max(cz-1, 0), zhi = min(cz+1, GRIDC-1);
    int ncand = 0, qslot0 = 0;
    bool overflow = false;
#pragma unroll
    for (int k = 0; k < 9; ++k) {
        int x = cx + dxo[k], y = cy + dyo[k];
        if ((unsigned)x >= GRIDC || (unsigned)y >= GRIDC) continue;
        int c0 = (x * GRIDC + y) * GRIDC;
        int b0 = cstart[c0 + zlo], e0 = cstart[c0 + zhi + 1];
        int len = e0 - b0;
        if (k == 0) qslot0 = qb - b0;              // center col staged at offset 0
        if (ncand + len > CAND_CAP) { len = CAND_CAP - ncand; overflow = true; }
        for (int i = tid; i < len; i += 64) cand[ncand + i] = sorted[b0 + i];
        ncand += len;
    }
    __syncthreads();

    const float inv_sigma = 1.0f / (2.1f * 0.05f);

    for (int qbase = 0; qbase < qn; qbase += 64) {
        const bool active = (qbase + tid) < qn;
        const float4 q = cand[active ? (qslot0 + qbase + tid) : 0];

        float kd[KNN]; int ki[KNN];
#pragma unroll
        for (int u = 0; u < KNN; ++u) { kd[u] = R0SQ; ki[u] = -1; }

        auto insert = [&](float d, int ci) {
            float cd = d;
#pragma unroll
            for (int u = 0; u < KNN; ++u) {
                bool lt = cd < kd[u];
                float td = kd[u]; int ti = ki[u];
                if (lt) { kd[u] = cd; ki[u] = ci; cd = td; ci = ti; }
            }
        };

        // ---- main scan: wave-uniform bounds, LDS broadcast reads
        if (!overflow) {
            for (int j = 0; j < ncand; ++j) {
                float4 s = cand[j];
                float dx = q.x - s.x, dy = q.y - s.y, dz = q.z - s.z;
                float d = dx * dx;
                d = fmaf(dy, dy, d);
                d = fmaf(dz, dz, d);
                if (active && d < kd[KNN-1]) insert(d, j);
            }
        }

        // ---- rare exact fallback (sentinel left => d10 > r0, or staging overflow)
        // Full per-lane redo from global with ring expansion; exact when
        // kd[9] <= (r*CELLK)^2 after scanning Chebyshev radius r.
        bool fb = active && (overflow || ki[KNN-1] < 0);
        if (fb) {
#pragma unroll
            for (int u = 0; u < KNN; ++u) { kd[u] = 3.4e38f; ki[u] = -1; }
            auto scanCol = [&](int x, int y, int z0, int z1) {
                if ((unsigned)x >= GRIDC || (unsigned)y >= GRIDC) return;
                z0 = max(z0, 0); z1 = min(z1, GRIDC - 1);
                if (z0 > z1) return;
                int cc = (x * GRIDC + y) * GRIDC;
                int b0 = cstart[cc + z0], e0 = cstart[cc + z1 + 1];
                for (int j = b0; j < e0; ++j) {
                    float4 s = sorted[j];
                    float dx = q.x - s.x, dy = q.y - s.y, dz = q.z - s.z;
                    float d = dx * dx;
                    d = fmaf(dy, dy, d);
                    d = fmaf(dz, dz, d);
                    if (d < kd[KNN-1]) insert(d, j + 1024);   // global row tag
                }
            };
            for (int xx = cx-1; xx <= cx+1; ++xx)
                for (int yy = cy-1; yy <= cy+1; ++yy)
                    scanCol(xx, yy, cz-1, cz+1);
            int r = 1;
            while (r < GRIDC && kd[KNN-1] > (r*CELLK)*(r*CELLK)) {
                ++r;
                for (int xx = cx-r; xx <= cx+r; ++xx)
                    for (int yy = cy-r; yy <= cy+r; ++yy) {
                        int ch = max(abs(xx-cx), abs(yy-cy));
                        if (ch == r) scanCol(xx, yy, cz-r, cz+r);
                        else { scanCol(xx, yy, cz-r, cz-r); scanCol(xx, yy, cz+r, cz+r); }
                    }
            }
        }

        // ---- KPConv influence sums
        float acc[PK];
#pragma unroll
        for (int p = 0; p < PK; ++p) acc[p] = 0.f;

        if (active) {
#pragma unroll
            for (int u = 0; u < KNN; ++u) {
                int idx = ki[u];
                float4 s;
                if (idx >= 1024)      s = sorted[idx - 1024];
                else if (idx >= 0)    s = cand[idx];
                else                  continue;           // unreachable safety
                float rx = s.x - q.x, ry = s.y - q.y, rz = s.z - q.z;
#pragma unroll
                for (int p = 0; p < PK; ++p) {
                    float ddx = rx - kpt[p].x, ddy = ry - kpt[p].y, ddz = rz - kpt[p].z;
                    float d2 = ddx * ddx;
                    d2 = fmaf(ddy, ddy, d2);
                    d2 = fmaf(ddz, ddz, d2);
                    acc[p] += fmaxf(0.f, 1.f - sqrtf(d2) * inv_sigma);
                }
            }

            // pooling voxel id: match jax exactly (fp32 division, floor)
            int gx = (int)floorf(q.x / 0.1f);
            int gy = (int)floorf(q.y / 0.1f);
            int gz = (int)floorf(q.z / 0.1f);
            gx = min(max(gx, 0), GRIDB - 1);
            gy = min(max(gy, 0), GRIDB - 1);
            gz = min(max(gz, 0), GRIDB - 1);
            const int seg = (gx * GRIDB + gy) * GRIDB + gz;

            float* counts = pool;
            float* spt    = pool + NSEG;
            float* sinf   = pool + NSEG * 4;
            atomicAdd(&counts[seg], 1.0f);
            atomicAdd(&spt[seg*3+0], q.x);
            atomicAdd(&spt[seg*3+1], q.y);
            atomicAdd(&spt[seg*3+2], q.z);
#pragma unroll
            for (int p = 0; p < PK; ++p) atomicAdd(&sinf[seg*PK + p], acc[p]);
        }
    }
}

__global__ __launch_bounds__(64) void finalize(
    const float* __restrict__ pool,
    const float* __restrict__ W,
    float* __restrict__ out)
{
    const int s = blockIdx.x;
    const int d = threadIdx.x;
    __shared__ float sInfl[PK];
    if (d < PK) sInfl[d] = pool[NSEG*4 + s*PK + d];
    __syncthreads();

    float c = fmaxf(pool[s], 1.0f);
    float inv = 1.0f / c;

    float a = 0.f;
#pragma unroll
    for (int p = 0; p < PK; ++p) a = fmaf(sInfl[p], W[p*NCOUT + d], a);
    out[NSEG*3 + s*NCOUT + d] = a * inv;

    if (d < 3) out[s*3 + d] = pool[NSEG + s*3 + d] * inv;
}

extern "C" void kernel_launch(void* const* d_in, const int* in_sizes, int n_in,
                              void* d_out, int out_size, void* d_ws, size_t ws_size,
                              hipStream_t stream)
{
    const float* pts  = (const float*)d_in[0];
    const float* kern = (const float*)d_in[1];
    const float* W    = (const float*)d_in[2];
    float* out = (float*)d_out;
    char*  ws  = (char*)d_ws;

    float4* sorted = (float4*)(ws + OFF_SORTED);
    int*    hist   = (int*)   (ws + OFF_HIST);
    int*    cstart = (int*)   (ws + OFF_CSTART);
    int*    cursor = (int*)   (ws + OFF_CURSOR);
    float*  pool   = (float*) (ws + OFF_POOL);

    hipMemsetAsync(hist, 0, NCELL * sizeof(int), stream);
    hipMemsetAsync(pool, 0, NSEG * (1 + 3 + PK) * sizeof(float), stream);

    hist_kernel    <<<NPTS/256, 256, 0, stream>>>(pts, hist);
    scan_kernel    <<<1,        256, 0, stream>>>(hist, cstart, cursor);
    scatter_kernel <<<NPTS/256, 256, 0, stream>>>(pts, cursor, sorted);
    knn_kpconv_pool<<<NCELL,     64, 0, stream>>>(sorted, cstart, kern, pool);
    finalize       <<<NSEG,      64, 0, stream>>>(pool, W, out);
}

// Round 4
// 356.015 us; speedup vs baseline: 1.2261x; 1.2261x over previous
//
#include <hip/hip_runtime.h>
#include <math.h>

#define NPTS  65536
#define KNN   10
#define PK    25
#define NCOUT 64
#define GRIDB 10          // pooling grid (cell 0.1) — must match reference
#define NSEG  1000
#define GRIDC 20          // kNN search grid (cell 0.05)
#define NCELL (GRIDC*GRIDC*GRIDC)
#define CELLK 0.05f
#define CAND_CAP 384      // LDS candidate buffer (ring-1 mean 221, +11 sigma)
#define QCAP  40          // queries per superbatch (P(cell>40 pts) ~ 1e-17)
#define NSTR  8           // candidate stripes per query
#define QG    8           // queries per pass (NSTR*QG = 64)

// ---- workspace layout (bytes) ----
#define OFF_SORTED  0           // float4 sorted[65536]
#define OFF_HIST    1048576     // int hist[8000]
#define OFF_CSTART  1080576     // int cstart[8001]
#define OFF_CURSOR  1112580     // int cursor[8000]
#define OFF_POOL    1144592     // float: counts[1000] | spt[1000*3] | sinf[1000*25]

__device__ __forceinline__ int cell_of(float px, float py, float pz) {
    int gx = min((int)(px * (float)GRIDC), GRIDC - 1);
    int gy = min((int)(py * (float)GRIDC), GRIDC - 1);
    int gz = min((int)(pz * (float)GRIDC), GRIDC - 1);
    return (gx * GRIDC + gy) * GRIDC + gz;
}

__global__ __launch_bounds__(256) void hist_kernel(
    const float* __restrict__ pts, int* __restrict__ hist)
{
    int g = blockIdx.x * 256 + threadIdx.x;
    float px = pts[g*3+0], py = pts[g*3+1], pz = pts[g*3+2];
    atomicAdd(&hist[cell_of(px, py, pz)], 1);
}

__global__ __launch_bounds__(256) void scan_kernel(
    const int* __restrict__ hist, int* __restrict__ cstart, int* __restrict__ cursor)
{
    __shared__ int part[256];
    const int t = threadIdx.x;
    const int base = t * 32;                       // 256*32 = 8192 >= 8000
    int s = 0;
    for (int i = 0; i < 32; ++i) {
        int c = base + i;
        s += (c < NCELL) ? hist[c] : 0;
    }
    part[t] = s;
    __syncthreads();
    for (int off = 1; off < 256; off <<= 1) {
        int v = (t >= off) ? part[t - off] : 0;
        __syncthreads();
        part[t] += v;
        __syncthreads();
    }
    int run = (t == 0) ? 0 : part[t - 1];
    for (int i = 0; i < 32; ++i) {
        int c = base + i;
        if (c < NCELL) {
            cstart[c] = run;
            cursor[c] = run;
            run += hist[c];
        }
    }
    if (t == 255) cstart[NCELL] = run;
}

__global__ __launch_bounds__(256) void scatter_kernel(
    const float* __restrict__ pts, int* __restrict__ cursor, float4* __restrict__ sorted)
{
    int g = blockIdx.x * 256 + threadIdx.x;
    float px = pts[g*3+0], py = pts[g*3+1], pz = pts[g*3+2];
    int c = cell_of(px, py, pz);
    int pos = atomicAdd(&cursor[c], 1);
    sorted[pos] = make_float4(px, py, pz, 0.f);
}

__device__ __forceinline__ void insert10(float (&kd)[KNN], int (&ki)[KNN],
                                         float d, int idx)
{
    float cd = d; int ci = idx;
#pragma unroll
    for (int u = 0; u < KNN; ++u) {
        bool lt = cd < kd[u];                  // strict: stable (earlier wins ties)
        float td = kd[u]; int ti = ki[u];
        kd[u] = lt ? cd : kd[u];
        ki[u] = lt ? ci : ki[u];
        cd = lt ? td : cd;
        ci = lt ? ti : ci;
    }
}

// One wave per fine cell. lane = (query_slot qi = tid>>3, stripe st = tid&7).
__global__ __launch_bounds__(64) void knn_kpconv_pool(
    const float4* __restrict__ sorted,
    const int*    __restrict__ cstart,
    const float*  __restrict__ kern,
    float*        __restrict__ pool)
{
    __shared__ float4 cand[CAND_CAP];
    __shared__ float  kx[PK], ky[PK], kz[PK];
    __shared__ float  md[QG][NSTR][KNN];
    __shared__ int    mi[QG][NSTR][KNN];
    __shared__ float  fd[QCAP][KNN];
    __shared__ int    fi[QCAP][KNN];

    const int tid = threadIdx.x;
    const int qi  = tid >> 3;
    const int st  = tid & 7;

    const int c  = blockIdx.x;
    const int cz = c % GRIDC;
    const int cy = (c / GRIDC) % GRIDC;
    const int cx = c / (GRIDC * GRIDC);
    const int qb = cstart[c], qe = cstart[c + 1];
    const int qn = qe - qb;
    if (qn == 0) return;

    if (tid < PK) {
        kx[tid] = kern[tid*3+0];
        ky[tid] = kern[tid*3+1];
        kz[tid] = kern[tid*3+2];
    }

    const float inv_sigma = 1.0f / (2.1f * 0.05f);
    float* counts = pool;
    float* spt    = pool + NSEG;
    float* sinf   = pool + NSEG * 4;

    for (int sb = 0; sb < qn; sb += QCAP) {
        const int qn_sb = min(qn - sb, QCAP);

        // ---- stage ring-1 (3^3 block) in ascending global-index order ----
        int ncand = 0;
        {
            int zlo = max(cz-1, 0), zhi = min(cz+1, GRIDC-1);
            for (int xx = max(cx-1,0); xx <= min(cx+1,GRIDC-1); ++xx)
                for (int yy = max(cy-1,0); yy <= min(cy+1,GRIDC-1); ++yy) {
                    int col = (xx * GRIDC + yy) * GRIDC;
                    int b0 = cstart[col + zlo], e0 = cstart[col + zhi + 1];
                    int len = e0 - b0;
                    if (ncand + len > CAND_CAP) len = CAND_CAP - ncand; // ~never
                    for (int i = tid; i < len; i += 64) {
                        float4 p = sorted[b0 + i];
                        p.w = __int_as_float(b0 + i);
                        cand[ncand + i] = p;
                    }
                    ncand += len;
                }
        }
        __syncthreads();

        // ---- Phase A: ring-1 stripe scan + merge per query group ----
        for (int g = 0; g < qn_sb; g += QG) {
            const int sq  = g + qi;
            const bool act = sq < qn_sb;
            const float4 Q = sorted[qb + sb + (act ? sq : 0)];

            float kd[KNN]; int ki[KNN];
#pragma unroll
            for (int u = 0; u < KNN; ++u) { kd[u] = 3.4e38f; ki[u] = -1; }

            const int L  = (ncand + NSTR - 1) / NSTR;
            const int lo = st * L, hi = min(lo + L, ncand);
            for (int j = lo; j < hi; ++j) {
                float4 sc = cand[j];
                float dx = Q.x - sc.x, dy = Q.y - sc.y, dz = Q.z - sc.z;
                float d = dx * dx;
                d = fmaf(dy, dy, d);
                d = fmaf(dz, dz, d);
                insert10(kd, ki, d, __float_as_int(sc.w));   // unguarded: any-lane ~1
            }
#pragma unroll
            for (int u = 0; u < KNN; ++u) { md[qi][st][u] = kd[u]; mi[qi][st][u] = ki[u]; }
            __syncthreads();

            if (st == 0) {
                float gd[KNN]; int gi_[KNN];
#pragma unroll
                for (int u = 0; u < KNN; ++u) { gd[u] = 3.4e38f; gi_[u] = -1; }
                for (int ss = 0; ss < NSTR; ++ss)
#pragma unroll
                    for (int u = 0; u < KNN; ++u) {
                        int cidx = mi[qi][ss][u];
                        if (cidx >= 0) insert10(gd, gi_, md[qi][ss][u], cidx);
                    }
                if (act) {
#pragma unroll
                    for (int u = 0; u < KNN; ++u) { fd[sq][u] = gd[u]; fi[sq][u] = gi_[u]; }
                }
            }
            __syncthreads();
        }

        // ---- Phase B: wave-uniform staged ring expansion (exact iff d10 <= (r*c)^2)
        int ring = 1;
        while (true) {
            float r2 = (ring * CELLK) * (ring * CELLK);
            bool mine = (tid < qn_sb) && (fd[tid][KNN-1] > r2);
            if (!__any(mine) || ring >= GRIDC) break;
            ++ring;

            int fill = 0;
            auto flush = [&](int nchunk) {
                __syncthreads();
                for (int g = 0; g < qn_sb; g += QG) {
                    const int sq  = g + qi;
                    const bool act = sq < qn_sb;
                    const int rsq = act ? sq : 0;
                    const float4 Q = sorted[qb + sb + rsq];
                    float kd[KNN]; int ki[KNN];
                    float bound = fd[rsq][KNN-1];
                    if (st == 0) {
#pragma unroll
                        for (int u = 0; u < KNN; ++u) { kd[u] = fd[rsq][u]; ki[u] = fi[rsq][u]; }
                    } else {
#pragma unroll
                        for (int u = 0; u < KNN; ++u) { kd[u] = bound; ki[u] = -1; }
                    }
                    const int L  = (nchunk + NSTR - 1) / NSTR;
                    const int lo = st * L, hi = min(lo + L, nchunk);
                    for (int j = lo; j < hi; ++j) {
                        float4 sc = cand[j];
                        float dx = Q.x - sc.x, dy = Q.y - sc.y, dz = Q.z - sc.z;
                        float d = dx * dx;
                        d = fmaf(dy, dy, d);
                        d = fmaf(dz, dz, d);
                        if (d < kd[KNN-1]) insert10(kd, ki, d, __float_as_int(sc.w));
                    }
#pragma unroll
                    for (int u = 0; u < KNN; ++u) { md[qi][st][u] = kd[u]; mi[qi][st][u] = ki[u]; }
                    __syncthreads();
                    if (st == 0) {
                        float gd[KNN]; int gi_[KNN];
#pragma unroll
                        for (int u = 0; u < KNN; ++u) { gd[u] = 3.4e38f; gi_[u] = -1; }
                        for (int ss = 0; ss < NSTR; ++ss)
#pragma unroll
                            for (int u = 0; u < KNN; ++u) {
                                int cidx = mi[qi][ss][u];
                                if (cidx >= 0) insert10(gd, gi_, md[qi][ss][u], cidx);
                            }
                        if (act) {
#pragma unroll
                            for (int u = 0; u < KNN; ++u) { fd[sq][u] = gd[u]; fi[sq][u] = gi_[u]; }
                        }
                    }
                    __syncthreads();
                }
            };

            for (int xx = max(cx-ring,0); xx <= min(cx+ring,GRIDC-1); ++xx)
                for (int yy = max(cy-ring,0); yy <= min(cy+ring,GRIDC-1); ++yy) {
                    int chxy = max(abs(xx-cx), abs(yy-cy));
                    int zr0[2], zr1[2]; int ns = 0;
                    if (chxy == ring) {
                        zr0[0] = max(cz-ring,0); zr1[0] = min(cz+ring,GRIDC-1); ns = 1;
                    } else {
                        if (cz-ring >= 0)      { zr0[ns] = cz-ring; zr1[ns] = cz-ring; ++ns; }
                        if (cz+ring <= GRIDC-1){ zr0[ns] = cz+ring; zr1[ns] = cz+ring; ++ns; }
                    }
                    for (int t = 0; t < ns; ++t) {
                        int col = (xx * GRIDC + yy) * GRIDC;
                        int b0 = cstart[col + zr0[t]], e0 = cstart[col + zr1[t] + 1];
                        int pos = b0;
                        while (pos < e0) {
                            int take = min(e0 - pos, CAND_CAP - fill);
                            for (int i = tid; i < take; i += 64) {
                                float4 p = sorted[pos + i];
                                p.w = __int_as_float(pos + i);
                                cand[fill + i] = p;
                            }
                            fill += take; pos += take;
                            if (fill == CAND_CAP) { flush(fill); fill = 0; }
                        }
                    }
                }
            if (fill > 0) { flush(fill); fill = 0; }
        }

        // ---- Phase C: influence + stripe reduce + pooling atomics ----
        for (int g = 0; g < qn_sb; g += QG) {
            const int sq  = g + qi;
            const bool act = sq < qn_sb;
            const float4 Q = sorted[qb + sb + (act ? sq : 0)];

            float acc[PK];
#pragma unroll
            for (int p = 0; p < PK; ++p) acc[p] = 0.f;

            if (act) {
#pragma unroll
                for (int r = 0; r < 2; ++r) {
                    int u = st + 8 * r;
                    if (u < KNN) {
                        int gidx = fi[sq][u];
                        if (gidx >= 0) {
                            float4 nb = sorted[gidx];
                            float rx = nb.x - Q.x, ry = nb.y - Q.y, rz = nb.z - Q.z;
#pragma unroll
                            for (int p = 0; p < PK; ++p) {
                                float ddx = rx - kx[p], ddy = ry - ky[p], ddz = rz - kz[p];
                                float d2 = ddx * ddx;
                                d2 = fmaf(ddy, ddy, d2);
                                d2 = fmaf(ddz, ddz, d2);
                                acc[p] += fmaxf(0.f, 1.f - sqrtf(d2) * inv_sigma);
                            }
                        }
                    }
                }
            }
#pragma unroll
            for (int p = 0; p < PK; ++p) {
                float v = acc[p];
                v += __shfl_xor(v, 1);
                v += __shfl_xor(v, 2);
                v += __shfl_xor(v, 4);
                acc[p] = v;
            }
            if (act && st == 0) {
                int gx = min(max((int)floorf(Q.x / 0.1f), 0), GRIDB - 1);
                int gy = min(max((int)floorf(Q.y / 0.1f), 0), GRIDB - 1);
                int gz = min(max((int)floorf(Q.z / 0.1f), 0), GRIDB - 1);
                const int seg = (gx * GRIDB + gy) * GRIDB + gz;
                atomicAdd(&counts[seg], 1.0f);
                atomicAdd(&spt[seg*3+0], Q.x);
                atomicAdd(&spt[seg*3+1], Q.y);
                atomicAdd(&spt[seg*3+2], Q.z);
#pragma unroll
                for (int p = 0; p < PK; ++p) atomicAdd(&sinf[seg*PK + p], acc[p]);
            }
        }
    }
}

__global__ __launch_bounds__(64) void finalize(
    const float* __restrict__ pool,
    const float* __restrict__ W,
    float* __restrict__ out)
{
    const int s = blockIdx.x;
    const int d = threadIdx.x;
    __shared__ float sInfl[PK];
    if (d < PK) sInfl[d] = pool[NSEG*4 + s*PK + d];
    __syncthreads();

    float c = fmaxf(pool[s], 1.0f);
    float inv = 1.0f / c;

    float a = 0.f;
#pragma unroll
    for (int p = 0; p < PK; ++p) a = fmaf(sInfl[p], W[p*NCOUT + d], a);
    out[NSEG*3 + s*NCOUT + d] = a * inv;

    if (d < 3) out[s*3 + d] = pool[NSEG + s*3 + d] * inv;
}

extern "C" void kernel_launch(void* const* d_in, const int* in_sizes, int n_in,
                              void* d_out, int out_size, void* d_ws, size_t ws_size,
                              hipStream_t stream)
{
    const float* pts  = (const float*)d_in[0];
    const float* kern = (const float*)d_in[1];
    const float* W    = (const float*)d_in[2];
    float* out = (float*)d_out;
    char*  ws  = (char*)d_ws;

    float4* sorted = (float4*)(ws + OFF_SORTED);
    int*    hist   = (int*)   (ws + OFF_HIST);
    int*    cstart = (int*)   (ws + OFF_CSTART);
    int*    cursor = (int*)   (ws + OFF_CURSOR);
    float*  pool   = (float*) (ws + OFF_POOL);

    hipMemsetAsync(hist, 0, NCELL * sizeof(int), stream);
    hipMemsetAsync(pool, 0, NSEG * (1 + 3 + PK) * sizeof(float), stream);

    hist_kernel    <<<NPTS/256, 256, 0, stream>>>(pts, hist);
    scan_kernel    <<<1,        256, 0, stream>>>(hist, cstart, cursor);
    scatter_kernel <<<NPTS/256, 256, 0, stream>>>(pts, cursor, sorted);
    knn_kpconv_pool<<<NCELL,     64, 0, stream>>>(sorted, cstart, kern, pool);
    finalize       <<<NSEG,      64, 0, stream>>>(pool, W, out);
}